// Round 17
// baseline (371.081 us; speedup 1.0000x reference)
//
#include <hip/hip_runtime.h>
#include <math.h>

#define NB   8
#define NPTS 1024
#define PTS  8192      // NB*NPTS
#define KNN  16
#define PK   (PTS*KNN) // 131072

typedef __attribute__((ext_vector_type(8))) _Float16 f16x8;
typedef __attribute__((ext_vector_type(4))) float f32x4;

__device__ __forceinline__ unsigned short f2h(float f) {
  _Float16 h = (_Float16)f;
  union { _Float16 h; unsigned short u; } c; c.h = h;
  return c.u;
}
__device__ __forceinline__ float h2f(unsigned short u) {
  union { unsigned short u; _Float16 h; } c; c.u = u;
  return (float)c.h;
}

// ---------------- kNN + conv1 layer1 fused: one WAVE per point ----------------
__global__ __launch_bounds__(256) void knn_conv1_kernel(const float* __restrict__ pos,
    const float* __restrict__ W1, const float* __restrict__ b1,
    int* __restrict__ idx, float* __restrict__ rel,
    unsigned short* __restrict__ z1h, float* __restrict__ mid1) {
  __shared__ float px[NPTS], py[NPTS], pz[NPTS];
  __shared__ float feat[4][KNN][6];
  __shared__ float ls[256], ls2[256];
  const int t = threadIdx.x;
  const int wv = t >> 6, lane = t & 63;
  const int b = blockIdx.x;
  const int graph = b >> 8;             // 256 blocks per graph
  const int base = graph << 10;
  for (int j = t; j < NPTS; j += 256) {
    px[j] = pos[3*(base+j)];
    py[j] = pos[3*(base+j)+1];
    pz[j] = pos[3*(base+j)+2];
  }
  __syncthreads();

  const int il = ((b & 255) << 2) + wv; // point index within graph
  const int i  = base + il;             // global point
  const float pix = px[il], piy = py[il], piz = pz[il];
  const float sqi = pix*pix + piy*piy + piz*piz;

  unsigned long long key[16];
  #pragma unroll
  for (int q = 0; q < 16; ++q) {
    const int j = (q << 6) + lane;
    const float x = px[j], y = py[j], z = pz[j];
    const float sqj = x*x + y*y + z*z;
    const float dt  = pix*x + piy*y + piz*z;
    const float d   = sqi + sqj - 2.0f*dt;
    unsigned int db = __float_as_uint(d);
    db = (db >> 31) ? ~db : (db | 0x80000000u);
    key[q] = ((unsigned long long)db << 32) | (unsigned int)j;
  }

  #pragma unroll
  for (int k = 2; k <= 16; k <<= 1) {
    #pragma unroll
    for (int jj = k >> 1; jj > 0; jj >>= 1) {
      #pragma unroll
      for (int ii = 0; ii < 16; ++ii) {
        const int l = ii ^ jj;
        if (l > ii) {
          const bool up = ((ii & k) == 0);
          const unsigned long long a = key[ii], c = key[l];
          const bool sw = up ? (c < a) : (a < c);
          key[ii] = sw ? c : a;
          key[l]  = sw ? a : c;
        }
      }
    }
  }

  #pragma unroll
  for (int m = 1; m <= 32; m <<= 1) {
    unsigned long long pk[16];
    #pragma unroll
    for (int ii = 0; ii < 16; ++ii) pk[ii] = __shfl_xor(key[ii], m);
    #pragma unroll
    for (int ii = 0; ii < 16; ++ii) {
      const unsigned long long o = pk[15 - ii];
      key[ii] = (o < key[ii]) ? o : key[ii];
    }
    #pragma unroll
    for (int s = 8; s >= 1; s >>= 1) {
      #pragma unroll
      for (int ii = 0; ii < 16; ++ii) {
        if ((ii & s) == 0) {
          const unsigned long long a = key[ii], c = key[ii | s];
          key[ii]     = (c < a) ? c : a;
          key[ii | s] = (c < a) ? a : c;
        }
      }
    }
  }

  int selj = 0;
  #pragma unroll
  for (int s = 0; s < 16; ++s)
    if (lane == s) selj = (int)(key[s] & 1023u);

  if (lane < KNN) {
    const int r = i*KNN + lane;
    const float rx = px[selj] - pix, ry = py[selj] - piy, rz = pz[selj] - piz;
    idx[r] = base + selj;
    rel[3*r] = rx; rel[3*r+1] = ry; rel[3*r+2] = rz;
    feat[wv][lane][0] = px[selj]; feat[wv][lane][1] = py[selj]; feat[wv][lane][2] = pz[selj];
    feat[wv][lane][3] = rx;       feat[wv][lane][4] = ry;       feat[wv][lane][5] = rz;
  }

  float w[6];
  #pragma unroll
  for (int q = 0; q < 6; ++q) w[q] = W1[q*64 + lane];
  const float bb = b1[lane];
  float s = 0.0f, s2 = 0.0f;
  #pragma unroll
  for (int k = 0; k < KNN; ++k) {
    float z = bb;
    #pragma unroll
    for (int q = 0; q < 6; ++q) z += feat[wv][k][q]*w[q];
    z1h[(size_t)(i*KNN + k)*64 + lane] = f2h(z);
    s += z; s2 += z*z;
  }
  ls[t] = s; ls2[t] = s2;
  __syncthreads();
  if (t < 64) {
    float a  = ls[t] + ls[t+64] + ls[t+128] + ls[t+192];
    float a2 = ls2[t] + ls2[t+64] + ls2[t+128] + ls2[t+192];
    atomicAdd(&mid1[t], a);
    atomicAdd(&mid1[64 + t], a2);
  }
}

// ---------------- weight prep ----------------
__global__ __launch_bounds__(256) void wprep_kernel(const float* __restrict__ W3,
    const float* __restrict__ W2, const float* __restrict__ W1c2,
    const float* __restrict__ W2c1,
    unsigned short* __restrict__ W3T, unsigned short* __restrict__ W2T,
    unsigned short* __restrict__ w1T, unsigned short* __restrict__ W2c1T) {
  const int b = blockIdx.x, t = threadIdx.x;
  if (b < 128) {
    for (int n = t; n < 1024; n += 256) W3T[n*128 + b] = f2h(W3[(size_t)b*1024 + n]);
  } else if (b < 132) {
    for (int id = (b-128)*2048 + t; id < (b-127)*2048; id += 256) {
      const int n = id >> 6, k = id & 63;
      W2T[n*64 + k] = f2h(W2[k*128 + n]);
    }
  } else if (b < 136) {
    for (int id = (b-132)*1024 + t; id < (b-131)*1024; id += 256) {
      const int n = id >> 6, k = id & 63;
      w1T[n*64 + k] = f2h(W1c2[k*64 + n]);
    }
  } else {
    for (int id = (b-136)*1024 + t; id < (b-135)*1024; id += 256) {
      const int n = id >> 6, k = id & 63;
      W2c1T[n*64 + k] = f2h(W2c1[k*64 + n]);
    }
  }
}

// inline BN finalize: channel c stats from mid (sum at mid[c], sumsq at mid[C+c])
__device__ __forceinline__ void bn_ss(const float* mid, const float* gamma,
                                      const float* beta, int C, int c,
                                      float invRows, float& sc, float& sh) {
  const float mu  = mid[c] * invRows;
  const float var = mid[C + c] * invRows - mu*mu;
  sc = gamma[c] * rsqrtf(var + 1e-5f);
  sh = beta[c] - mu*sc;
}

// ---------------- conv1 layer2 + max: fp16 MFMA, inline BN stats ----------------
__global__ __launch_bounds__(256) void conv1_l2max_mfma(
    const unsigned short* __restrict__ z1h, const float* __restrict__ mid1,
    const float* __restrict__ g1, const float* __restrict__ be1,
    const unsigned short* __restrict__ W2T, const float* __restrict__ b2,
    unsigned short* __restrict__ x1h) {
  __shared__ unsigned short As[128*64];
  const int r0 = blockIdx.x * 128;
  const int t = threadIdx.x;
  const int lane = t & 63, w = t >> 6;
  const int quad = lane >> 4, mcol = lane & 15;
  const float invR = 1.0f / (float)PK;

  {
    const int kb = t & 7, rr = t >> 3;
    float sc[8], sh[8];
    #pragma unroll
    for (int q = 0; q < 8; ++q) bn_ss(mid1, g1, be1, 64, kb*8 + q, invR, sc[q], sh[q]);
    #pragma unroll
    for (int it = 0; it < 4; ++it) {
      const int r = rr + it*32;
      union { uint4 v; unsigned short s[8]; } in;
      in.v = *(const uint4*)(z1h + (size_t)(r0 + r)*64 + kb*8);
      union { unsigned short s[8]; uint4 v; } o;
      #pragma unroll
      for (int q = 0; q < 8; ++q)
        o.s[q] = f2h(fmaxf(h2f(in.s[q])*sc[q] + sh[q], 0.0f));
      *(uint4*)(As + r*64 + ((kb ^ (r & 7)) * 8)) = o.v;
    }
  }
  __syncthreads();

  const int wrow = (w >> 1) * 64;
  const int wncol = (w & 1) * 32;

  f32x4 acc[4][2];
  #pragma unroll
  for (int mi = 0; mi < 4; ++mi)
    #pragma unroll
    for (int ni = 0; ni < 2; ++ni)
      acc[mi][ni] = (f32x4){0.f, 0.f, 0.f, 0.f};

  #pragma unroll
  for (int ks = 0; ks < 2; ++ks) {
    f16x8 af[4], bfr[2];
    #pragma unroll
    for (int mi = 0; mi < 4; ++mi) {
      const int row = wrow + mi*16 + mcol;
      af[mi] = *(const f16x8*)(As + row*64 + (((ks*4 + quad) ^ (row & 7)) * 8));
    }
    #pragma unroll
    for (int ni = 0; ni < 2; ++ni) {
      const int nr = wncol + ni*16 + mcol;
      bfr[ni] = *(const f16x8*)(W2T + nr*64 + ks*32 + quad*8);
    }
    #pragma unroll
    for (int mi = 0; mi < 4; ++mi)
      #pragma unroll
      for (int ni = 0; ni < 2; ++ni)
        acc[mi][ni] = __builtin_amdgcn_mfma_f32_16x16x32_f16(af[mi], bfr[ni], acc[mi][ni], 0, 0, 0);
  }

  float bb[2];
  #pragma unroll
  for (int ni = 0; ni < 2; ++ni) bb[ni] = b2[wncol + ni*16 + mcol];
  #pragma unroll
  for (int mi = 0; mi < 4; ++mi) {
    const int p = blockIdx.x*8 + (w >> 1)*4 + mi;
    #pragma unroll
    for (int ni = 0; ni < 2; ++ni) {
      f32x4 a = acc[mi][ni];
      float m = fmaxf(fmaxf(a[0], a[1]), fmaxf(a[2], a[3]));
      m = fmaxf(m, __shfl_xor(m, 16));
      m = fmaxf(m, __shfl_xor(m, 32));
      if (quad == 0) x1h[(size_t)p*64 + wncol + ni*16 + mcol] = f2h(m + bb[ni]);
    }
  }
}

// ---------------- conv2 layer1: fp16 MFMA (gather + rank-3 rel fixup) + atomic BN partials ----------------
__global__ __launch_bounds__(256) void conv2_l1_mfma(
    const unsigned short* __restrict__ x1h, const int* __restrict__ idx,
    const float* __restrict__ rel, const unsigned short* __restrict__ w1T,
    const float* __restrict__ W1full, const float* __restrict__ b1,
    unsigned short* __restrict__ zah, float* __restrict__ midA) {
  __shared__ unsigned short S[128*64];
  __shared__ int   idxr[128];
  __shared__ float rl[128*3];
  __shared__ float ps[256];
  const int r0 = blockIdx.x * 128;
  const int t = threadIdx.x;
  const int lane = t & 63, w = t >> 6;
  const int quad = lane >> 4, mcol = lane & 15;

  if (t < 128) idxr[t] = idx[r0 + t];
  else if (t < 224) *(float4*)(rl + (t-128)*4) = *(const float4*)(rel + (size_t)r0*3 + (t-128)*4);
  __syncthreads();

  {
    const int kb = t & 7, rr = t >> 3;
    #pragma unroll
    for (int it = 0; it < 4; ++it) {
      const int r = rr + it*32;
      const int gj = idxr[r];
      const uint4 v = *(const uint4*)(x1h + (size_t)gj*64 + kb*8);
      *(uint4*)(S + r*64 + ((kb ^ (r & 7)) * 8)) = v;
    }
  }
  __syncthreads();

  const int wrow = (w >> 1) * 64;
  const int wcol = (w & 1) * 32;

  f16x8 af[2][4], bfr[2][2];
  #pragma unroll
  for (int ks = 0; ks < 2; ++ks)
    #pragma unroll
    for (int mi = 0; mi < 4; ++mi) {
      const int row = wrow + mi*16 + mcol;
      af[ks][mi] = *(const f16x8*)(S + row*64 + (((ks*4 + quad) ^ (row & 7)) * 8));
    }
  #pragma unroll
  for (int ks = 0; ks < 2; ++ks)
    #pragma unroll
    for (int ni = 0; ni < 2; ++ni) {
      const int nr = wcol + ni*16 + mcol;
      bfr[ks][ni] = *(const f16x8*)(w1T + nr*64 + ks*32 + quad*8);
    }

  f32x4 acc[4][2];
  #pragma unroll
  for (int mi = 0; mi < 4; ++mi)
    #pragma unroll
    for (int ni = 0; ni < 2; ++ni)
      acc[mi][ni] = (f32x4){0.f, 0.f, 0.f, 0.f};

  #pragma unroll
  for (int ks = 0; ks < 2; ++ks)
    #pragma unroll
    for (int mi = 0; mi < 4; ++mi)
      #pragma unroll
      for (int ni = 0; ni < 2; ++ni)
        acc[mi][ni] = __builtin_amdgcn_mfma_f32_16x16x32_f16(af[ks][mi], bfr[ks][ni], acc[mi][ni], 0, 0, 0);

  __syncthreads();

  float bb[2], wr0[2], wr1[2], wr2[2];
  #pragma unroll
  for (int ni = 0; ni < 2; ++ni) {
    const int col = wcol + ni*16 + mcol;
    bb[ni]  = b1[col];
    wr0[ni] = W1full[64*64 + col];
    wr1[ni] = W1full[65*64 + col];
    wr2[ni] = W1full[66*64 + col];
  }
  float s[2] = {0,0}, s2[2] = {0,0};
  #pragma unroll
  for (int mi = 0; mi < 4; ++mi) {
    #pragma unroll
    for (int j = 0; j < 4; ++j) {
      const int row = wrow + mi*16 + quad*4 + j;
      const float r0v = rl[row*3], r1v = rl[row*3+1], r2v = rl[row*3+2];
      #pragma unroll
      for (int ni = 0; ni < 2; ++ni) {
        const int col = wcol + ni*16 + mcol;
        const int g = col >> 3, o = col & 7;
        const float v = acc[mi][ni][j] + bb[ni] + r0v*wr0[ni] + r1v*wr1[ni] + r2v*wr2[ni];
        S[row*64 + ((g ^ (row & 7)) << 3) + o] = f2h(v);
        s[ni] += v; s2[ni] += v*v;
      }
    }
  }
  #pragma unroll
  for (int ni = 0; ni < 2; ++ni) {
    s[ni]  += __shfl_xor(s[ni], 16);  s[ni]  += __shfl_xor(s[ni], 32);
    s2[ni] += __shfl_xor(s2[ni], 16); s2[ni] += __shfl_xor(s2[ni], 32);
  }
  if (quad == 0) {
    const int rh = w >> 1;
    #pragma unroll
    for (int ni = 0; ni < 2; ++ni) {
      const int col = wcol + ni*16 + mcol;
      ps[rh*128 + col]      = s[ni];
      ps[rh*128 + 64 + col] = s2[ni];
    }
  }
  __syncthreads();

  #pragma unroll
  for (int i = 0; i < 4; ++i) {
    const int u = i*256 + t;
    const int row = u >> 3, gg = u & 7;
    *(uint4*)(zah + (size_t)(r0 + row)*64 + gg*8) =
        *(const uint4*)(S + row*64 + ((gg ^ (row & 7)) << 3));
  }
  if (t < 128) atomicAdd(&midA[t], ps[t] + ps[128 + t]);
}

// ---------------- conv2 layer2: fp16 MFMA, inline BN stats + atomic BN partials out ----------------
__global__ __launch_bounds__(256) void conv2_l2_mfma(
    const unsigned short* __restrict__ zah, const float* __restrict__ midA,
    const float* __restrict__ g1, const float* __restrict__ be1,
    const unsigned short* __restrict__ W2T, const float* __restrict__ b2,
    unsigned short* __restrict__ zhb, float* __restrict__ midB) {
  __shared__ unsigned short S[128*128];
  __shared__ float ps[512];
  const int r0 = blockIdx.x * 128;
  const int t = threadIdx.x;
  const int lane = t & 63, w = t >> 6;
  const int quad = lane >> 4, mcol = lane & 15;
  const float invR = 1.0f / (float)PK;

  {
    const int kb = t & 7, rr = t >> 3;
    float sc[8], sh[8];
    #pragma unroll
    for (int q = 0; q < 8; ++q) bn_ss(midA, g1, be1, 64, kb*8 + q, invR, sc[q], sh[q]);
    #pragma unroll
    for (int it = 0; it < 4; ++it) {
      const int r = rr + it*32;
      union { uint4 v; unsigned short s[8]; } in;
      in.v = *(const uint4*)(zah + (size_t)(r0 + r)*64 + kb*8);
      union { unsigned short s[8]; uint4 v; } o;
      #pragma unroll
      for (int q = 0; q < 8; ++q)
        o.s[q] = f2h(fmaxf(h2f(in.s[q])*sc[q] + sh[q], 0.0f));
      *(uint4*)(S + r*64 + ((kb ^ (r & 7)) * 8)) = o.v;
    }
  }
  __syncthreads();

  const int wrow = (w >> 1) * 64;
  const int wcol = (w & 1) * 64;

  f16x8 af[2][4], bfr[2][4];
  #pragma unroll
  for (int ks = 0; ks < 2; ++ks)
    #pragma unroll
    for (int mi = 0; mi < 4; ++mi) {
      const int row = wrow + mi*16 + mcol;
      af[ks][mi] = *(const f16x8*)(S + row*64 + (((ks*4 + quad) ^ (row & 7)) * 8));
    }
  #pragma unroll
  for (int ks = 0; ks < 2; ++ks)
    #pragma unroll
    for (int ni = 0; ni < 4; ++ni) {
      const int nr = wcol + ni*16 + mcol;
      bfr[ks][ni] = *(const f16x8*)(W2T + nr*64 + ks*32 + quad*8);
    }

  f32x4 acc[4][4];
  #pragma unroll
  for (int mi = 0; mi < 4; ++mi)
    #pragma unroll
    for (int ni = 0; ni < 4; ++ni)
      acc[mi][ni] = (f32x4){0.f, 0.f, 0.f, 0.f};

  #pragma unroll
  for (int ks = 0; ks < 2; ++ks)
    #pragma unroll
    for (int mi = 0; mi < 4; ++mi)
      #pragma unroll
      for (int ni = 0; ni < 4; ++ni)
        acc[mi][ni] = __builtin_amdgcn_mfma_f32_16x16x32_f16(af[ks][mi], bfr[ks][ni], acc[mi][ni], 0, 0, 0);

  __syncthreads();

  float bb[4];
  #pragma unroll
  for (int ni = 0; ni < 4; ++ni) bb[ni] = b2[wcol + ni*16 + mcol];
  float s[4] = {0,0,0,0}, s2[4] = {0,0,0,0};
  #pragma unroll
  for (int mi = 0; mi < 4; ++mi) {
    #pragma unroll
    for (int ni = 0; ni < 4; ++ni) {
      const int col = wcol + ni*16 + mcol;
      const int g = col >> 3, o = col & 7;
      #pragma unroll
      for (int j = 0; j < 4; ++j) {
        const int row = wrow + mi*16 + quad*4 + j;
        const float v = acc[mi][ni][j] + bb[ni];
        S[row*128 + ((g ^ (row & 15)) << 3) + o] = f2h(v);
        s[ni] += v; s2[ni] += v*v;
      }
    }
  }
  #pragma unroll
  for (int ni = 0; ni < 4; ++ni) {
    s[ni]  += __shfl_xor(s[ni], 16);  s[ni]  += __shfl_xor(s[ni], 32);
    s2[ni] += __shfl_xor(s2[ni], 16); s2[ni] += __shfl_xor(s2[ni], 32);
  }
  if (quad == 0) {
    const int rh = w >> 1;
    #pragma unroll
    for (int ni = 0; ni < 4; ++ni) {
      const int col = wcol + ni*16 + mcol;
      ps[rh*256 + col]       = s[ni];
      ps[rh*256 + 128 + col] = s2[ni];
    }
  }
  __syncthreads();

  #pragma unroll
  for (int i = 0; i < 8; ++i) {
    const int u = i*256 + t;
    const int row = u >> 4, gg = u & 15;
    *(uint4*)(zhb + (size_t)(r0 + row)*128 + gg*8) =
        *(const uint4*)(S + row*128 + ((gg ^ (row & 15)) << 3));
  }
  atomicAdd(&midB[t], ps[t] + ps[256 + t]);
}

// ---------------- conv2 layer3 + full max fusion: chunk-paired af reuse ----------------
// 2048 blocks: rb = bid & 1023 (128 rows), ch = bid >> 10 (512-col half).
// 4 chunk-pairs of 2x64 cols; per ks, af loaded ONCE and fed to both chunks
// (halves A-tile ds_reads vs round 13). acc 2x32=64 AGPR + af 16 + bfr 16 ~ fits (256,3).
// NOTE: full 2-deep B double-buffer (64 VGPR) spills — do not reintroduce.
__global__ __launch_bounds__(256, 3) void conv2_l3max_mfma(
    const unsigned short* __restrict__ zhb, const float* __restrict__ midB,
    const float* __restrict__ g2, const float* __restrict__ be2,
    const unsigned short* __restrict__ W3T,
    float* __restrict__ pmax2) {
  __shared__ unsigned short As[128*128];
  __shared__ float pm[1024];   // [rowhalf][512]
  const int rb = blockIdx.x & 1023, ch = blockIdx.x >> 10;
  const int r0 = rb * 128;
  const int t = threadIdx.x;
  const int lane = t & 63, w = t >> 6;
  const int quad = lane >> 4, mcol = lane & 15;
  const float invR = 1.0f / (float)PK;

  #pragma unroll
  for (int i = 0; i < 4; ++i) pm[i*256 + t] = -INFINITY;

  // ---- stage A: relu(bn(zhb)) fp16 -> fp16, swizzled; BN finalized inline ----
  {
    const int kb = t & 15, rr = t >> 4;
    float sc[8], sh[8];
    #pragma unroll
    for (int q = 0; q < 8; ++q) bn_ss(midB, g2, be2, 128, kb*8 + q, invR, sc[q], sh[q]);
    #pragma unroll
    for (int it = 0; it < 8; ++it) {
      const int r = rr + it*16;
      union { uint4 v; unsigned short s[8]; } in;
      in.v = *(const uint4*)(zhb + (size_t)(r0 + r)*128 + kb*8);
      union { unsigned short s[8]; uint4 v; } o;
      #pragma unroll
      for (int q = 0; q < 8; ++q)
        o.s[q] = f2h(fmaxf(h2f(in.s[q])*sc[q] + sh[q], 0.0f));
      *(uint4*)(As + r*128 + ((kb ^ (r & 7)) * 8)) = o.v;
    }
  }
  __syncthreads();

  const int wrow = (w >> 1) * 64;
  const int wncol = (w & 1) * 32;
  const int rh = w >> 1;

  #pragma unroll 1
  for (int cp = 0; cp < 4; ++cp) {         // chunk pair: chunks 2*cp, 2*cp+1
    const int n0 = ch*512 + cp*128;

    f32x4 acc[4][2][2];   // [mi][ci][ni]
    #pragma unroll
    for (int mi = 0; mi < 4; ++mi)
      #pragma unroll
      for (int ci = 0; ci < 2; ++ci)
        #pragma unroll
        for (int ni = 0; ni < 2; ++ni)
          acc[mi][ci][ni] = (f32x4){0.f, 0.f, 0.f, 0.f};

    #pragma unroll
    for (int ks = 0; ks < 4; ++ks) {
      f16x8 bfr[2][2], af[4];
      #pragma unroll
      for (int ci = 0; ci < 2; ++ci)
        #pragma unroll
        for (int ni = 0; ni < 2; ++ni) {
          const int nr = n0 + ci*64 + wncol + ni*16 + mcol;
          bfr[ci][ni] = *(const f16x8*)(W3T + (size_t)nr*128 + ks*32 + quad*8);
        }
      #pragma unroll
      for (int mi = 0; mi < 4; ++mi) {
        const int row = wrow + mi*16 + mcol;
        af[mi] = *(const f16x8*)(As + row*128 + (((ks*4 + quad) ^ (row & 7)) * 8));
      }
      #pragma unroll
      for (int mi = 0; mi < 4; ++mi)
        #pragma unroll
        for (int ci = 0; ci < 2; ++ci)
          #pragma unroll
          for (int ni = 0; ni < 2; ++ni)
            acc[mi][ci][ni] = __builtin_amdgcn_mfma_f32_16x16x32_f16(af[mi], bfr[ci][ni], acc[mi][ci][ni], 0, 0, 0);
    }

    // max over this wave's 64 rows per column; fmax-accumulate into pm
    #pragma unroll
    for (int ci = 0; ci < 2; ++ci) {
      #pragma unroll
      for (int ni = 0; ni < 2; ++ni) {
        float m4 = -INFINITY;
        #pragma unroll
        for (int mi = 0; mi < 4; ++mi) {
          f32x4 a = acc[mi][ci][ni];
          m4 = fmaxf(m4, fmaxf(fmaxf(a[0], a[1]), fmaxf(a[2], a[3])));
        }
        m4 = fmaxf(m4, __shfl_xor(m4, 16));
        m4 = fmaxf(m4, __shfl_xor(m4, 32));
        if (quad == 0) {
          const int pc = rh*512 + (cp*2 + ci)*64 + wncol + ni*16 + mcol;
          pm[pc] = fmaxf(pm[pc], m4);
        }
      }
    }
  }
  __syncthreads();

  pmax2[(size_t)rb*1024 + ch*512 + t]       = fmaxf(pm[t], pm[512 + t]);
  pmax2[(size_t)rb*1024 + ch*512 + 256 + t] = fmaxf(pm[256 + t], pm[768 + t]);
}

// ---------------- final pool: max over 128 row-blocks per graph + b3 ----------------
__global__ __launch_bounds__(256) void pool_final_kernel(const float* __restrict__ pmax2,
    const float* __restrict__ b3, float* __restrict__ g) {
  const int b = blockIdx.x >> 2, q = blockIdx.x & 3;
  const int c = q*256 + threadIdx.x;
  const float* p = pmax2 + (size_t)b*128*1024 + c;
  float m = -INFINITY;
  for (int rb = 0; rb < 128; ++rb) m = fmaxf(m, p[(size_t)rb*1024]);
  g[b*1024 + c] = m + b3[c];
}

// ---------------- final linear (partials over c-quarters) ----------------
__global__ __launch_bounds__(256) void lin_kernel(const float* __restrict__ g,
    const float* __restrict__ W, float* __restrict__ zpart) {
  const int b = blockIdx.x >> 2, q = blockIdx.x & 3;
  const int o = threadIdx.x;
  const float* gb = g + b*1024 + q*256;
  const float* Wq = W + q*256*256;
  float acc = 0.0f;
  for (int c = 0; c < 256; ++c) acc += gb[c] * Wq[c*256 + o];
  zpart[blockIdx.x*256 + o] = acc;
}

// ---------------- final BN(8 rows) + relu ----------------
__global__ __launch_bounds__(256) void final_kernel(const float* __restrict__ zpart,
    const float* __restrict__ lb, const float* __restrict__ lg,
    const float* __restrict__ lbe, float* __restrict__ out) {
  const int o = threadIdx.x;
  float z[NB]; float s = 0.0f, s2 = 0.0f;
  #pragma unroll
  for (int b = 0; b < NB; ++b) {
    float v = lb[o];
    #pragma unroll
    for (int q = 0; q < 4; ++q) v += zpart[(b*4+q)*256 + o];
    z[b] = v; s += v; s2 += v*v;
  }
  const float mu  = s * 0.125f;
  const float var = s2 * 0.125f - mu*mu;
  const float inv = rsqrtf(var + 1e-5f);
  const float sc = lg[o]*inv, sh = lbe[o] - mu*sc;
  #pragma unroll
  for (int b = 0; b < NB; ++b) out[b*256 + o] = fmaxf(z[b]*sc + sh, 0.0f);
}

extern "C" void kernel_launch(void* const* d_in, const int* in_sizes, int n_in,
                              void* d_out, int out_size, void* d_ws, size_t ws_size,
                              hipStream_t stream) {
  const float* pos    = (const float*)d_in[0];
  const float* c1_W1  = (const float*)d_in[2];
  const float* c1_b1  = (const float*)d_in[3];
  const float* c1_g1  = (const float*)d_in[4];
  const float* c1_be1 = (const float*)d_in[5];
  const float* c1_W2  = (const float*)d_in[6];
  const float* c1_b2  = (const float*)d_in[7];
  const float* c2_W1  = (const float*)d_in[8];
  const float* c2_b1  = (const float*)d_in[9];
  const float* c2_g1  = (const float*)d_in[10];
  const float* c2_be1 = (const float*)d_in[11];
  const float* c2_W2  = (const float*)d_in[12];
  const float* c2_b2  = (const float*)d_in[13];
  const float* c2_g2  = (const float*)d_in[14];
  const float* c2_be2 = (const float*)d_in[15];
  const float* c2_W3  = (const float*)d_in[16];
  const float* c2_b3  = (const float*)d_in[17];
  const float* lin_W  = (const float*)d_in[18];
  const float* lin_b  = (const float*)d_in[19];
  const float* lin_g  = (const float*)d_in[20];
  const float* lin_be = (const float*)d_in[21];
  float* out = (float*)d_out;

  char* ws = (char*)d_ws;
  int*   idx     = (int*)  (ws + 0);                 // 512 KB
  float* rel     = (float*)(ws + 524288);            // 1.5 MB
  float* zpart   = (float*)(ws + 2097152 + 2048);    // 8192
  float* gpool   = (float*)(ws + 2097152 + 2048 + 32768);          // 8192
  float* mid1    = (float*)(ws + 2164736);           // 128   } zeroed
  float* midA    = (float*)(ws + 2164736 + 512);     // 128   } by one
  float* midB    = (float*)(ws + 2164736 + 1024);    // 256   } memset
  unsigned short* W2T   = (unsigned short*)(ws + 2295808);  // 16 KB (conv2 W2)
  unsigned short* w1T   = (unsigned short*)(ws + 2312192);  // 8 KB  (conv2 W1 cols 0..63)
  unsigned short* W2c1T = (unsigned short*)(ws + 2320384);  // 8 KB  (conv1 W2)
  unsigned short* z1h = (unsigned short*)(ws + 2426880);
  unsigned short* zah = (unsigned short*)(ws + 2426880);
  float* pmax2   = (float*)(ws + 2426880);
  unsigned short* x1h = (unsigned short*)(ws + 35981312);  // 1 MB fp16
  unsigned short* zhb = (unsigned short*)(ws + 38078464);  // 33.5 MB fp16 zb
  unsigned short* W3T = (unsigned short*)(ws + 71632896);  // 256 KB

  hipMemsetAsync(ws + 2164736, 0, 2048, stream);   // zero mid1/midA/midB
  wprep_kernel<<<140, 256, 0, stream>>>(c2_W3, c2_W2, c2_W1, c1_W2, W3T, W2T, w1T, W2c1T);
  knn_conv1_kernel<<<PTS/4, 256, 0, stream>>>(pos, c1_W1, c1_b1, idx, rel, z1h, mid1);
  conv1_l2max_mfma<<<PK/128, 256, 0, stream>>>(z1h, mid1, c1_g1, c1_be1, W2c1T, c1_b2, x1h);
  conv2_l1_mfma<<<PK/128, 256, 0, stream>>>(x1h, idx, rel, w1T, c2_W1, c2_b1, zah, midA);
  conv2_l2_mfma<<<PK/128, 256, 0, stream>>>(zah, midA, c2_g1, c2_be1, W2T, c2_b2, zhb, midB);
  conv2_l3max_mfma<<<PK/64, 256, 0, stream>>>(zhb, midB, c2_g2, c2_be2, W3T, pmax2);
  pool_final_kernel<<<NB*4, 256, 0, stream>>>(pmax2, c2_b3, gpool);
  lin_kernel<<<32, 256, 0, stream>>>(gpool, lin_W, zpart);
  final_kernel<<<1, 256, 0, stream>>>(zpart, lin_b, lin_g, lin_be, out);
}

// Round 18
// 354.412 us; speedup vs baseline: 1.0470x; 1.0470x over previous
//
#include <hip/hip_runtime.h>
#include <math.h>

#define NB   8
#define NPTS 1024
#define PTS  8192      // NB*NPTS
#define KNN  16
#define PK   (PTS*KNN) // 131072

typedef __attribute__((ext_vector_type(8))) _Float16 f16x8;
typedef __attribute__((ext_vector_type(4))) float f32x4;

__device__ __forceinline__ unsigned short f2h(float f) {
  _Float16 h = (_Float16)f;
  union { _Float16 h; unsigned short u; } c; c.h = h;
  return c.u;
}
__device__ __forceinline__ float h2f(unsigned short u) {
  union { unsigned short u; _Float16 h; } c; c.u = u;
  return (float)c.h;
}

// ---------------- kNN + conv1 layer1 fused: one WAVE per point ----------------
__global__ __launch_bounds__(256) void knn_conv1_kernel(const float* __restrict__ pos,
    const float* __restrict__ W1, const float* __restrict__ b1,
    int* __restrict__ idx, float* __restrict__ rel,
    unsigned short* __restrict__ z1h, float* __restrict__ mid1) {
  __shared__ float px[NPTS], py[NPTS], pz[NPTS];
  __shared__ float feat[4][KNN][6];
  __shared__ float ls[256], ls2[256];
  const int t = threadIdx.x;
  const int wv = t >> 6, lane = t & 63;
  const int b = blockIdx.x;
  const int graph = b >> 8;             // 256 blocks per graph
  const int base = graph << 10;
  for (int j = t; j < NPTS; j += 256) {
    px[j] = pos[3*(base+j)];
    py[j] = pos[3*(base+j)+1];
    pz[j] = pos[3*(base+j)+2];
  }
  __syncthreads();

  const int il = ((b & 255) << 2) + wv; // point index within graph
  const int i  = base + il;             // global point
  const float pix = px[il], piy = py[il], piz = pz[il];
  const float sqi = pix*pix + piy*piy + piz*piz;

  unsigned long long key[16];
  #pragma unroll
  for (int q = 0; q < 16; ++q) {
    const int j = (q << 6) + lane;
    const float x = px[j], y = py[j], z = pz[j];
    const float sqj = x*x + y*y + z*z;
    const float dt  = pix*x + piy*y + piz*z;
    const float d   = sqi + sqj - 2.0f*dt;
    unsigned int db = __float_as_uint(d);
    db = (db >> 31) ? ~db : (db | 0x80000000u);
    key[q] = ((unsigned long long)db << 32) | (unsigned int)j;
  }

  #pragma unroll
  for (int k = 2; k <= 16; k <<= 1) {
    #pragma unroll
    for (int jj = k >> 1; jj > 0; jj >>= 1) {
      #pragma unroll
      for (int ii = 0; ii < 16; ++ii) {
        const int l = ii ^ jj;
        if (l > ii) {
          const bool up = ((ii & k) == 0);
          const unsigned long long a = key[ii], c = key[l];
          const bool sw = up ? (c < a) : (a < c);
          key[ii] = sw ? c : a;
          key[l]  = sw ? a : c;
        }
      }
    }
  }

  #pragma unroll
  for (int m = 1; m <= 32; m <<= 1) {
    unsigned long long pk[16];
    #pragma unroll
    for (int ii = 0; ii < 16; ++ii) pk[ii] = __shfl_xor(key[ii], m);
    #pragma unroll
    for (int ii = 0; ii < 16; ++ii) {
      const unsigned long long o = pk[15 - ii];
      key[ii] = (o < key[ii]) ? o : key[ii];
    }
    #pragma unroll
    for (int s = 8; s >= 1; s >>= 1) {
      #pragma unroll
      for (int ii = 0; ii < 16; ++ii) {
        if ((ii & s) == 0) {
          const unsigned long long a = key[ii], c = key[ii | s];
          key[ii]     = (c < a) ? c : a;
          key[ii | s] = (c < a) ? a : c;
        }
      }
    }
  }

  int selj = 0;
  #pragma unroll
  for (int s = 0; s < 16; ++s)
    if (lane == s) selj = (int)(key[s] & 1023u);

  if (lane < KNN) {
    const int r = i*KNN + lane;
    const float rx = px[selj] - pix, ry = py[selj] - piy, rz = pz[selj] - piz;
    idx[r] = base + selj;
    rel[3*r] = rx; rel[3*r+1] = ry; rel[3*r+2] = rz;
    feat[wv][lane][0] = px[selj]; feat[wv][lane][1] = py[selj]; feat[wv][lane][2] = pz[selj];
    feat[wv][lane][3] = rx;       feat[wv][lane][4] = ry;       feat[wv][lane][5] = rz;
  }

  float w[6];
  #pragma unroll
  for (int q = 0; q < 6; ++q) w[q] = W1[q*64 + lane];
  const float bb = b1[lane];
  float s = 0.0f, s2 = 0.0f;
  #pragma unroll
  for (int k = 0; k < KNN; ++k) {
    float z = bb;
    #pragma unroll
    for (int q = 0; q < 6; ++q) z += feat[wv][k][q]*w[q];
    z1h[(size_t)(i*KNN + k)*64 + lane] = f2h(z);
    s += z; s2 += z*z;
  }
  ls[t] = s; ls2[t] = s2;
  __syncthreads();
  if (t < 64) {
    float a  = ls[t] + ls[t+64] + ls[t+128] + ls[t+192];
    float a2 = ls2[t] + ls2[t+64] + ls2[t+128] + ls2[t+192];
    atomicAdd(&mid1[t], a);
    atomicAdd(&mid1[64 + t], a2);
  }
}

// ---------------- weight prep ----------------
__global__ __launch_bounds__(256) void wprep_kernel(const float* __restrict__ W3,
    const float* __restrict__ W2, const float* __restrict__ W1c2,
    const float* __restrict__ W2c1,
    unsigned short* __restrict__ W3T, unsigned short* __restrict__ W2T,
    unsigned short* __restrict__ w1T, unsigned short* __restrict__ W2c1T) {
  const int b = blockIdx.x, t = threadIdx.x;
  if (b < 128) {
    for (int n = t; n < 1024; n += 256) W3T[n*128 + b] = f2h(W3[(size_t)b*1024 + n]);
  } else if (b < 132) {
    for (int id = (b-128)*2048 + t; id < (b-127)*2048; id += 256) {
      const int n = id >> 6, k = id & 63;
      W2T[n*64 + k] = f2h(W2[k*128 + n]);
    }
  } else if (b < 136) {
    for (int id = (b-132)*1024 + t; id < (b-131)*1024; id += 256) {
      const int n = id >> 6, k = id & 63;
      w1T[n*64 + k] = f2h(W1c2[k*64 + n]);
    }
  } else {
    for (int id = (b-136)*1024 + t; id < (b-135)*1024; id += 256) {
      const int n = id >> 6, k = id & 63;
      W2c1T[n*64 + k] = f2h(W2c1[k*64 + n]);
    }
  }
}

// inline BN finalize: channel c stats from mid (sum at mid[c], sumsq at mid[C+c])
__device__ __forceinline__ void bn_ss(const float* mid, const float* gamma,
                                      const float* beta, int C, int c,
                                      float invRows, float& sc, float& sh) {
  const float mu  = mid[c] * invRows;
  const float var = mid[C + c] * invRows - mu*mu;
  sc = gamma[c] * rsqrtf(var + 1e-5f);
  sh = beta[c] - mu*sc;
}

// ---------------- conv1 layer2 + max: fp16 MFMA, inline BN stats ----------------
__global__ __launch_bounds__(256) void conv1_l2max_mfma(
    const unsigned short* __restrict__ z1h, const float* __restrict__ mid1,
    const float* __restrict__ g1, const float* __restrict__ be1,
    const unsigned short* __restrict__ W2T, const float* __restrict__ b2,
    unsigned short* __restrict__ x1h) {
  __shared__ unsigned short As[128*64];
  const int r0 = blockIdx.x * 128;
  const int t = threadIdx.x;
  const int lane = t & 63, w = t >> 6;
  const int quad = lane >> 4, mcol = lane & 15;
  const float invR = 1.0f / (float)PK;

  {
    const int kb = t & 7, rr = t >> 3;
    float sc[8], sh[8];
    #pragma unroll
    for (int q = 0; q < 8; ++q) bn_ss(mid1, g1, be1, 64, kb*8 + q, invR, sc[q], sh[q]);
    #pragma unroll
    for (int it = 0; it < 4; ++it) {
      const int r = rr + it*32;
      union { uint4 v; unsigned short s[8]; } in;
      in.v = *(const uint4*)(z1h + (size_t)(r0 + r)*64 + kb*8);
      union { unsigned short s[8]; uint4 v; } o;
      #pragma unroll
      for (int q = 0; q < 8; ++q)
        o.s[q] = f2h(fmaxf(h2f(in.s[q])*sc[q] + sh[q], 0.0f));
      *(uint4*)(As + r*64 + ((kb ^ (r & 7)) * 8)) = o.v;
    }
  }
  __syncthreads();

  const int wrow = (w >> 1) * 64;
  const int wncol = (w & 1) * 32;

  f32x4 acc[4][2];
  #pragma unroll
  for (int mi = 0; mi < 4; ++mi)
    #pragma unroll
    for (int ni = 0; ni < 2; ++ni)
      acc[mi][ni] = (f32x4){0.f, 0.f, 0.f, 0.f};

  #pragma unroll
  for (int ks = 0; ks < 2; ++ks) {
    f16x8 af[4], bfr[2];
    #pragma unroll
    for (int mi = 0; mi < 4; ++mi) {
      const int row = wrow + mi*16 + mcol;
      af[mi] = *(const f16x8*)(As + row*64 + (((ks*4 + quad) ^ (row & 7)) * 8));
    }
    #pragma unroll
    for (int ni = 0; ni < 2; ++ni) {
      const int nr = wncol + ni*16 + mcol;
      bfr[ni] = *(const f16x8*)(W2T + nr*64 + ks*32 + quad*8);
    }
    #pragma unroll
    for (int mi = 0; mi < 4; ++mi)
      #pragma unroll
      for (int ni = 0; ni < 2; ++ni)
        acc[mi][ni] = __builtin_amdgcn_mfma_f32_16x16x32_f16(af[mi], bfr[ni], acc[mi][ni], 0, 0, 0);
  }

  float bb[2];
  #pragma unroll
  for (int ni = 0; ni < 2; ++ni) bb[ni] = b2[wncol + ni*16 + mcol];
  #pragma unroll
  for (int mi = 0; mi < 4; ++mi) {
    const int p = blockIdx.x*8 + (w >> 1)*4 + mi;
    #pragma unroll
    for (int ni = 0; ni < 2; ++ni) {
      f32x4 a = acc[mi][ni];
      float m = fmaxf(fmaxf(a[0], a[1]), fmaxf(a[2], a[3]));
      m = fmaxf(m, __shfl_xor(m, 16));
      m = fmaxf(m, __shfl_xor(m, 32));
      if (quad == 0) x1h[(size_t)p*64 + wncol + ni*16 + mcol] = f2h(m + bb[ni]);
    }
  }
}

// ---------------- conv2 layer1: fp16 MFMA (gather + rank-3 rel fixup) + atomic BN partials ----------------
__global__ __launch_bounds__(256) void conv2_l1_mfma(
    const unsigned short* __restrict__ x1h, const int* __restrict__ idx,
    const float* __restrict__ rel, const unsigned short* __restrict__ w1T,
    const float* __restrict__ W1full, const float* __restrict__ b1,
    unsigned short* __restrict__ zah, float* __restrict__ midA) {
  __shared__ unsigned short S[128*64];
  __shared__ int   idxr[128];
  __shared__ float rl[128*3];
  __shared__ float ps[256];
  const int r0 = blockIdx.x * 128;
  const int t = threadIdx.x;
  const int lane = t & 63, w = t >> 6;
  const int quad = lane >> 4, mcol = lane & 15;

  if (t < 128) idxr[t] = idx[r0 + t];
  else if (t < 224) *(float4*)(rl + (t-128)*4) = *(const float4*)(rel + (size_t)r0*3 + (t-128)*4);
  __syncthreads();

  {
    const int kb = t & 7, rr = t >> 3;
    #pragma unroll
    for (int it = 0; it < 4; ++it) {
      const int r = rr + it*32;
      const int gj = idxr[r];
      const uint4 v = *(const uint4*)(x1h + (size_t)gj*64 + kb*8);
      *(uint4*)(S + r*64 + ((kb ^ (r & 7)) * 8)) = v;
    }
  }
  __syncthreads();

  const int wrow = (w >> 1) * 64;
  const int wcol = (w & 1) * 32;

  f16x8 af[2][4], bfr[2][2];
  #pragma unroll
  for (int ks = 0; ks < 2; ++ks)
    #pragma unroll
    for (int mi = 0; mi < 4; ++mi) {
      const int row = wrow + mi*16 + mcol;
      af[ks][mi] = *(const f16x8*)(S + row*64 + (((ks*4 + quad) ^ (row & 7)) * 8));
    }
  #pragma unroll
  for (int ks = 0; ks < 2; ++ks)
    #pragma unroll
    for (int ni = 0; ni < 2; ++ni) {
      const int nr = wcol + ni*16 + mcol;
      bfr[ks][ni] = *(const f16x8*)(w1T + nr*64 + ks*32 + quad*8);
    }

  f32x4 acc[4][2];
  #pragma unroll
  for (int mi = 0; mi < 4; ++mi)
    #pragma unroll
    for (int ni = 0; ni < 2; ++ni)
      acc[mi][ni] = (f32x4){0.f, 0.f, 0.f, 0.f};

  #pragma unroll
  for (int ks = 0; ks < 2; ++ks)
    #pragma unroll
    for (int mi = 0; mi < 4; ++mi)
      #pragma unroll
      for (int ni = 0; ni < 2; ++ni)
        acc[mi][ni] = __builtin_amdgcn_mfma_f32_16x16x32_f16(af[ks][mi], bfr[ks][ni], acc[mi][ni], 0, 0, 0);

  __syncthreads();

  float bb[2], wr0[2], wr1[2], wr2[2];
  #pragma unroll
  for (int ni = 0; ni < 2; ++ni) {
    const int col = wcol + ni*16 + mcol;
    bb[ni]  = b1[col];
    wr0[ni] = W1full[64*64 + col];
    wr1[ni] = W1full[65*64 + col];
    wr2[ni] = W1full[66*64 + col];
  }
  float s[2] = {0,0}, s2[2] = {0,0};
  #pragma unroll
  for (int mi = 0; mi < 4; ++mi) {
    #pragma unroll
    for (int j = 0; j < 4; ++j) {
      const int row = wrow + mi*16 + quad*4 + j;
      const float r0v = rl[row*3], r1v = rl[row*3+1], r2v = rl[row*3+2];
      #pragma unroll
      for (int ni = 0; ni < 2; ++ni) {
        const int col = wcol + ni*16 + mcol;
        const int g = col >> 3, o = col & 7;
        const float v = acc[mi][ni][j] + bb[ni] + r0v*wr0[ni] + r1v*wr1[ni] + r2v*wr2[ni];
        S[row*64 + ((g ^ (row & 7)) << 3) + o] = f2h(v);
        s[ni] += v; s2[ni] += v*v;
      }
    }
  }
  #pragma unroll
  for (int ni = 0; ni < 2; ++ni) {
    s[ni]  += __shfl_xor(s[ni], 16);  s[ni]  += __shfl_xor(s[ni], 32);
    s2[ni] += __shfl_xor(s2[ni], 16); s2[ni] += __shfl_xor(s2[ni], 32);
  }
  if (quad == 0) {
    const int rh = w >> 1;
    #pragma unroll
    for (int ni = 0; ni < 2; ++ni) {
      const int col = wcol + ni*16 + mcol;
      ps[rh*128 + col]      = s[ni];
      ps[rh*128 + 64 + col] = s2[ni];
    }
  }
  __syncthreads();

  #pragma unroll
  for (int i = 0; i < 4; ++i) {
    const int u = i*256 + t;
    const int row = u >> 3, gg = u & 7;
    *(uint4*)(zah + (size_t)(r0 + row)*64 + gg*8) =
        *(const uint4*)(S + row*64 + ((gg ^ (row & 7)) << 3));
  }
  if (t < 128) atomicAdd(&midA[t], ps[t] + ps[128 + t]);
}

// ---------------- conv2 layer2: fp16 MFMA, inline BN stats + atomic BN partials out ----------------
__global__ __launch_bounds__(256) void conv2_l2_mfma(
    const unsigned short* __restrict__ zah, const float* __restrict__ midA,
    const float* __restrict__ g1, const float* __restrict__ be1,
    const unsigned short* __restrict__ W2T, const float* __restrict__ b2,
    unsigned short* __restrict__ zhb, float* __restrict__ midB) {
  __shared__ unsigned short S[128*128];
  __shared__ float ps[512];
  const int r0 = blockIdx.x * 128;
  const int t = threadIdx.x;
  const int lane = t & 63, w = t >> 6;
  const int quad = lane >> 4, mcol = lane & 15;
  const float invR = 1.0f / (float)PK;

  {
    const int kb = t & 7, rr = t >> 3;
    float sc[8], sh[8];
    #pragma unroll
    for (int q = 0; q < 8; ++q) bn_ss(midA, g1, be1, 64, kb*8 + q, invR, sc[q], sh[q]);
    #pragma unroll
    for (int it = 0; it < 4; ++it) {
      const int r = rr + it*32;
      union { uint4 v; unsigned short s[8]; } in;
      in.v = *(const uint4*)(zah + (size_t)(r0 + r)*64 + kb*8);
      union { unsigned short s[8]; uint4 v; } o;
      #pragma unroll
      for (int q = 0; q < 8; ++q)
        o.s[q] = f2h(fmaxf(h2f(in.s[q])*sc[q] + sh[q], 0.0f));
      *(uint4*)(S + r*64 + ((kb ^ (r & 7)) * 8)) = o.v;
    }
  }
  __syncthreads();

  const int wrow = (w >> 1) * 64;
  const int wcol = (w & 1) * 64;

  f16x8 af[2][4], bfr[2][4];
  #pragma unroll
  for (int ks = 0; ks < 2; ++ks)
    #pragma unroll
    for (int mi = 0; mi < 4; ++mi) {
      const int row = wrow + mi*16 + mcol;
      af[ks][mi] = *(const f16x8*)(S + row*64 + (((ks*4 + quad) ^ (row & 7)) * 8));
    }
  #pragma unroll
  for (int ks = 0; ks < 2; ++ks)
    #pragma unroll
    for (int ni = 0; ni < 4; ++ni) {
      const int nr = wcol + ni*16 + mcol;
      bfr[ks][ni] = *(const f16x8*)(W2T + nr*64 + ks*32 + quad*8);
    }

  f32x4 acc[4][4];
  #pragma unroll
  for (int mi = 0; mi < 4; ++mi)
    #pragma unroll
    for (int ni = 0; ni < 4; ++ni)
      acc[mi][ni] = (f32x4){0.f, 0.f, 0.f, 0.f};

  #pragma unroll
  for (int ks = 0; ks < 2; ++ks)
    #pragma unroll
    for (int mi = 0; mi < 4; ++mi)
      #pragma unroll
      for (int ni = 0; ni < 4; ++ni)
        acc[mi][ni] = __builtin_amdgcn_mfma_f32_16x16x32_f16(af[ks][mi], bfr[ks][ni], acc[mi][ni], 0, 0, 0);

  __syncthreads();

  float bb[4];
  #pragma unroll
  for (int ni = 0; ni < 4; ++ni) bb[ni] = b2[wcol + ni*16 + mcol];
  float s[4] = {0,0,0,0}, s2[4] = {0,0,0,0};
  #pragma unroll
  for (int mi = 0; mi < 4; ++mi) {
    #pragma unroll
    for (int ni = 0; ni < 4; ++ni) {
      const int col = wcol + ni*16 + mcol;
      const int g = col >> 3, o = col & 7;
      #pragma unroll
      for (int j = 0; j < 4; ++j) {
        const int row = wrow + mi*16 + quad*4 + j;
        const float v = acc[mi][ni][j] + bb[ni];
        S[row*128 + ((g ^ (row & 15)) << 3) + o] = f2h(v);
        s[ni] += v; s2[ni] += v*v;
      }
    }
  }
  #pragma unroll
  for (int ni = 0; ni < 4; ++ni) {
    s[ni]  += __shfl_xor(s[ni], 16);  s[ni]  += __shfl_xor(s[ni], 32);
    s2[ni] += __shfl_xor(s2[ni], 16); s2[ni] += __shfl_xor(s2[ni], 32);
  }
  if (quad == 0) {
    const int rh = w >> 1;
    #pragma unroll
    for (int ni = 0; ni < 4; ++ni) {
      const int col = wcol + ni*16 + mcol;
      ps[rh*256 + col]       = s[ni];
      ps[rh*256 + 128 + col] = s2[ni];
    }
  }
  __syncthreads();

  #pragma unroll
  for (int i = 0; i < 8; ++i) {
    const int u = i*256 + t;
    const int row = u >> 4, gg = u & 15;
    *(uint4*)(zhb + (size_t)(r0 + row)*128 + gg*8) =
        *(const uint4*)(S + row*128 + ((gg ^ (row & 15)) << 3));
  }
  atomicAdd(&midB[t], ps[t] + ps[256 + t]);
}

// ---------------- conv2 layer3 + full max fusion: round-13 body + inline BN ----------------
// 2048 blocks: rb = bid & 1023 (128 rows), ch = bid >> 10 (512-col half).
// 8 chunks of 64 cols, acc[4][2] (32 AGPR), single-buffer B, pm LDS accumulate.
// NOTE (3x confirmed): any added per-iter register state (B double-buffer, paired
// accumulators) spills or drops occupancy — keep acc at 32 AGPR.
__global__ __launch_bounds__(256, 3) void conv2_l3max_mfma(
    const unsigned short* __restrict__ zhb, const float* __restrict__ midB,
    const float* __restrict__ g2, const float* __restrict__ be2,
    const unsigned short* __restrict__ W3T,
    float* __restrict__ pmax2) {
  __shared__ unsigned short As[128*128];
  __shared__ float pm[1024];   // [rowhalf][512]
  const int rb = blockIdx.x & 1023, ch = blockIdx.x >> 10;
  const int r0 = rb * 128;
  const int t = threadIdx.x;
  const int lane = t & 63, w = t >> 6;
  const int quad = lane >> 4, mcol = lane & 15;
  const float invR = 1.0f / (float)PK;

  #pragma unroll
  for (int i = 0; i < 4; ++i) pm[i*256 + t] = -INFINITY;

  {
    const int kb = t & 15, rr = t >> 4;
    float sc[8], sh[8];
    #pragma unroll
    for (int q = 0; q < 8; ++q) bn_ss(midB, g2, be2, 128, kb*8 + q, invR, sc[q], sh[q]);
    #pragma unroll
    for (int it = 0; it < 8; ++it) {
      const int r = rr + it*16;
      union { uint4 v; unsigned short s[8]; } in;
      in.v = *(const uint4*)(zhb + (size_t)(r0 + r)*128 + kb*8);
      union { unsigned short s[8]; uint4 v; } o;
      #pragma unroll
      for (int q = 0; q < 8; ++q)
        o.s[q] = f2h(fmaxf(h2f(in.s[q])*sc[q] + sh[q], 0.0f));
      *(uint4*)(As + r*128 + ((kb ^ (r & 7)) * 8)) = o.v;
    }
  }
  __syncthreads();

  const int wrow = (w >> 1) * 64;
  const int wncol = (w & 1) * 32;
  const int rh = w >> 1;

  #pragma unroll 1
  for (int chunk = 0; chunk < 8; ++chunk) {
    const int n0 = ch*512 + chunk*64;

    f32x4 acc[4][2];
    #pragma unroll
    for (int mi = 0; mi < 4; ++mi)
      #pragma unroll
      for (int ni = 0; ni < 2; ++ni)
        acc[mi][ni] = (f32x4){0.f, 0.f, 0.f, 0.f};

    #pragma unroll
    for (int ks = 0; ks < 4; ++ks) {
      f16x8 bfr[2], af[4];
      #pragma unroll
      for (int ni = 0; ni < 2; ++ni) {
        const int nr = n0 + wncol + ni*16 + mcol;
        bfr[ni] = *(const f16x8*)(W3T + (size_t)nr*128 + ks*32 + quad*8);
      }
      #pragma unroll
      for (int mi = 0; mi < 4; ++mi) {
        const int row = wrow + mi*16 + mcol;
        af[mi] = *(const f16x8*)(As + row*128 + (((ks*4 + quad) ^ (row & 7)) * 8));
      }
      #pragma unroll
      for (int mi = 0; mi < 4; ++mi)
        #pragma unroll
        for (int ni = 0; ni < 2; ++ni)
          acc[mi][ni] = __builtin_amdgcn_mfma_f32_16x16x32_f16(af[mi], bfr[ni], acc[mi][ni], 0, 0, 0);
    }

    #pragma unroll
    for (int ni = 0; ni < 2; ++ni) {
      float m4 = -INFINITY;
      #pragma unroll
      for (int mi = 0; mi < 4; ++mi) {
        f32x4 a = acc[mi][ni];
        m4 = fmaxf(m4, fmaxf(fmaxf(a[0], a[1]), fmaxf(a[2], a[3])));
      }
      m4 = fmaxf(m4, __shfl_xor(m4, 16));
      m4 = fmaxf(m4, __shfl_xor(m4, 32));
      if (quad == 0) {
        const int pc = rh*512 + chunk*64 + wncol + ni*16 + mcol;
        pm[pc] = fmaxf(pm[pc], m4);
      }
    }
  }
  __syncthreads();

  pmax2[(size_t)rb*1024 + ch*512 + t]       = fmaxf(pm[t], pm[512 + t]);
  pmax2[(size_t)rb*1024 + ch*512 + 256 + t] = fmaxf(pm[256 + t], pm[768 + t]);
}

// ---------------- final pool: max over 128 row-blocks per graph + b3 ----------------
__global__ __launch_bounds__(256) void pool_final_kernel(const float* __restrict__ pmax2,
    const float* __restrict__ b3, float* __restrict__ g) {
  const int b = blockIdx.x >> 2, q = blockIdx.x & 3;
  const int c = q*256 + threadIdx.x;
  const float* p = pmax2 + (size_t)b*128*1024 + c;
  float m = -INFINITY;
  for (int rb = 0; rb < 128; ++rb) m = fmaxf(m, p[(size_t)rb*1024]);
  g[b*1024 + c] = m + b3[c];
}

// ---------------- final linear (partials over c-quarters) ----------------
__global__ __launch_bounds__(256) void lin_kernel(const float* __restrict__ g,
    const float* __restrict__ W, float* __restrict__ zpart) {
  const int b = blockIdx.x >> 2, q = blockIdx.x & 3;
  const int o = threadIdx.x;
  const float* gb = g + b*1024 + q*256;
  const float* Wq = W + q*256*256;
  float acc = 0.0f;
  for (int c = 0; c < 256; ++c) acc += gb[c] * Wq[c*256 + o];
  zpart[blockIdx.x*256 + o] = acc;
}

// ---------------- final BN(8 rows) + relu ----------------
__global__ __launch_bounds__(256) void final_kernel(const float* __restrict__ zpart,
    const float* __restrict__ lb, const float* __restrict__ lg,
    const float* __restrict__ lbe, float* __restrict__ out) {
  const int o = threadIdx.x;
  float z[NB]; float s = 0.0f, s2 = 0.0f;
  #pragma unroll
  for (int b = 0; b < NB; ++b) {
    float v = lb[o];
    #pragma unroll
    for (int q = 0; q < 4; ++q) v += zpart[(b*4+q)*256 + o];
    z[b] = v; s += v; s2 += v*v;
  }
  const float mu  = s * 0.125f;
  const float var = s2 * 0.125f - mu*mu;
  const float inv = rsqrtf(var + 1e-5f);
  const float sc = lg[o]*inv, sh = lbe[o] - mu*sc;
  #pragma unroll
  for (int b = 0; b < NB; ++b) out[b*256 + o] = fmaxf(z[b]*sc + sh, 0.0f);
}

extern "C" void kernel_launch(void* const* d_in, const int* in_sizes, int n_in,
                              void* d_out, int out_size, void* d_ws, size_t ws_size,
                              hipStream_t stream) {
  const float* pos    = (const float*)d_in[0];
  const float* c1_W1  = (const float*)d_in[2];
  const float* c1_b1  = (const float*)d_in[3];
  const float* c1_g1  = (const float*)d_in[4];
  const float* c1_be1 = (const float*)d_in[5];
  const float* c1_W2  = (const float*)d_in[6];
  const float* c1_b2  = (const float*)d_in[7];
  const float* c2_W1  = (const float*)d_in[8];
  const float* c2_b1  = (const float*)d_in[9];
  const float* c2_g1  = (const float*)d_in[10];
  const float* c2_be1 = (const float*)d_in[11];
  const float* c2_W2  = (const float*)d_in[12];
  const float* c2_b2  = (const float*)d_in[13];
  const float* c2_g2  = (const float*)d_in[14];
  const float* c2_be2 = (const float*)d_in[15];
  const float* c2_W3  = (const float*)d_in[16];
  const float* c2_b3  = (const float*)d_in[17];
  const float* lin_W  = (const float*)d_in[18];
  const float* lin_b  = (const float*)d_in[19];
  const float* lin_g  = (const float*)d_in[20];
  const float* lin_be = (const float*)d_in[21];
  float* out = (float*)d_out;

  char* ws = (char*)d_ws;
  int*   idx     = (int*)  (ws + 0);                 // 512 KB
  float* rel     = (float*)(ws + 524288);            // 1.5 MB
  float* zpart   = (float*)(ws + 2097152 + 2048);    // 8192
  float* gpool   = (float*)(ws + 2097152 + 2048 + 32768);          // 8192
  float* mid1    = (float*)(ws + 2164736);           // 128   } zeroed
  float* midA    = (float*)(ws + 2164736 + 512);     // 128   } by one
  float* midB    = (float*)(ws + 2164736 + 1024);    // 256   } memset
  unsigned short* W2T   = (unsigned short*)(ws + 2295808);  // 16 KB (conv2 W2)
  unsigned short* w1T   = (unsigned short*)(ws + 2312192);  // 8 KB  (conv2 W1 cols 0..63)
  unsigned short* W2c1T = (unsigned short*)(ws + 2320384);  // 8 KB  (conv1 W2)
  unsigned short* z1h = (unsigned short*)(ws + 2426880);
  unsigned short* zah = (unsigned short*)(ws + 2426880);
  float* pmax2   = (float*)(ws + 2426880);
  unsigned short* x1h = (unsigned short*)(ws + 35981312);  // 1 MB fp16
  unsigned short* zhb = (unsigned short*)(ws + 38078464);  // 33.5 MB fp16 zb
  unsigned short* W3T = (unsigned short*)(ws + 71632896);  // 256 KB

  hipMemsetAsync(ws + 2164736, 0, 2048, stream);   // zero mid1/midA/midB
  wprep_kernel<<<140, 256, 0, stream>>>(c2_W3, c2_W2, c2_W1, c1_W2, W3T, W2T, w1T, W2c1T);
  knn_conv1_kernel<<<PTS/4, 256, 0, stream>>>(pos, c1_W1, c1_b1, idx, rel, z1h, mid1);
  conv1_l2max_mfma<<<PK/128, 256, 0, stream>>>(z1h, mid1, c1_g1, c1_be1, W2c1T, c1_b2, x1h);
  conv2_l1_mfma<<<PK/128, 256, 0, stream>>>(x1h, idx, rel, w1T, c2_W1, c2_b1, zah, midA);
  conv2_l2_mfma<<<PK/128, 256, 0, stream>>>(zah, midA, c2_g1, c2_be1, W2T, c2_b2, zhb, midB);
  conv2_l3max_mfma<<<PK/64, 256, 0, stream>>>(zhb, midB, c2_g2, c2_be2, W3T, pmax2);
  pool_final_kernel<<<NB*4, 256, 0, stream>>>(pmax2, c2_b3, gpool);
  lin_kernel<<<32, 256, 0, stream>>>(gpool, lin_W, zpart);
  final_kernel<<<1, 256, 0, stream>>>(zpart, lin_b, lin_g, lin_be, out);
}

// Round 19
// 283.614 us; speedup vs baseline: 1.3084x; 1.2496x over previous
//
#include <hip/hip_runtime.h>
#include <math.h>

#define NB   8
#define NPTS 1024
#define PTS  8192      // NB*NPTS
#define KNN  16
#define PK   (PTS*KNN) // 131072

typedef __attribute__((ext_vector_type(8))) _Float16 f16x8;
typedef __attribute__((ext_vector_type(4))) float f32x4;

__device__ __forceinline__ unsigned short f2h(float f) {
  _Float16 h = (_Float16)f;
  union { _Float16 h; unsigned short u; } c; c.h = h;
  return c.u;
}
__device__ __forceinline__ float h2f(unsigned short u) {
  union { unsigned short u; _Float16 h; } c; c.u = u;
  return (float)c.h;
}

// ---------------- kNN + conv1 layer1 fused: one WAVE per point ----------------
// BN partials go to 8 XCD-aligned copies (blockIdx&7) to kill atomic contention.
__global__ __launch_bounds__(256) void knn_conv1_kernel(const float* __restrict__ pos,
    const float* __restrict__ W1, const float* __restrict__ b1,
    int* __restrict__ idx, float* __restrict__ rel,
    unsigned short* __restrict__ z1h, float* __restrict__ mid1) {
  __shared__ float px[NPTS], py[NPTS], pz[NPTS];
  __shared__ float feat[4][KNN][6];
  __shared__ float ls[256], ls2[256];
  const int t = threadIdx.x;
  const int wv = t >> 6, lane = t & 63;
  const int b = blockIdx.x;
  const int graph = b >> 8;             // 256 blocks per graph
  const int base = graph << 10;
  for (int j = t; j < NPTS; j += 256) {
    px[j] = pos[3*(base+j)];
    py[j] = pos[3*(base+j)+1];
    pz[j] = pos[3*(base+j)+2];
  }
  __syncthreads();

  const int il = ((b & 255) << 2) + wv; // point index within graph
  const int i  = base + il;             // global point
  const float pix = px[il], piy = py[il], piz = pz[il];
  const float sqi = pix*pix + piy*piy + piz*piz;

  unsigned long long key[16];
  #pragma unroll
  for (int q = 0; q < 16; ++q) {
    const int j = (q << 6) + lane;
    const float x = px[j], y = py[j], z = pz[j];
    const float sqj = x*x + y*y + z*z;
    const float dt  = pix*x + piy*y + piz*z;
    const float d   = sqi + sqj - 2.0f*dt;
    unsigned int db = __float_as_uint(d);
    db = (db >> 31) ? ~db : (db | 0x80000000u);
    key[q] = ((unsigned long long)db << 32) | (unsigned int)j;
  }

  #pragma unroll
  for (int k = 2; k <= 16; k <<= 1) {
    #pragma unroll
    for (int jj = k >> 1; jj > 0; jj >>= 1) {
      #pragma unroll
      for (int ii = 0; ii < 16; ++ii) {
        const int l = ii ^ jj;
        if (l > ii) {
          const bool up = ((ii & k) == 0);
          const unsigned long long a = key[ii], c = key[l];
          const bool sw = up ? (c < a) : (a < c);
          key[ii] = sw ? c : a;
          key[l]  = sw ? a : c;
        }
      }
    }
  }

  #pragma unroll
  for (int m = 1; m <= 32; m <<= 1) {
    unsigned long long pk[16];
    #pragma unroll
    for (int ii = 0; ii < 16; ++ii) pk[ii] = __shfl_xor(key[ii], m);
    #pragma unroll
    for (int ii = 0; ii < 16; ++ii) {
      const unsigned long long o = pk[15 - ii];
      key[ii] = (o < key[ii]) ? o : key[ii];
    }
    #pragma unroll
    for (int s = 8; s >= 1; s >>= 1) {
      #pragma unroll
      for (int ii = 0; ii < 16; ++ii) {
        if ((ii & s) == 0) {
          const unsigned long long a = key[ii], c = key[ii | s];
          key[ii]     = (c < a) ? c : a;
          key[ii | s] = (c < a) ? a : c;
        }
      }
    }
  }

  int selj = 0;
  #pragma unroll
  for (int s = 0; s < 16; ++s)
    if (lane == s) selj = (int)(key[s] & 1023u);

  if (lane < KNN) {
    const int r = i*KNN + lane;
    const float rx = px[selj] - pix, ry = py[selj] - piy, rz = pz[selj] - piz;
    idx[r] = base + selj;
    rel[3*r] = rx; rel[3*r+1] = ry; rel[3*r+2] = rz;
    feat[wv][lane][0] = px[selj]; feat[wv][lane][1] = py[selj]; feat[wv][lane][2] = pz[selj];
    feat[wv][lane][3] = rx;       feat[wv][lane][4] = ry;       feat[wv][lane][5] = rz;
  }

  float w[6];
  #pragma unroll
  for (int q = 0; q < 6; ++q) w[q] = W1[q*64 + lane];
  const float bb = b1[lane];
  float s = 0.0f, s2 = 0.0f;
  #pragma unroll
  for (int k = 0; k < KNN; ++k) {
    float z = bb;
    #pragma unroll
    for (int q = 0; q < 6; ++q) z += feat[wv][k][q]*w[q];
    z1h[(size_t)(i*KNN + k)*64 + lane] = f2h(z);
    s += z; s2 += z*z;
  }
  ls[t] = s; ls2[t] = s2;
  __syncthreads();
  if (t < 64) {
    float a  = ls[t] + ls[t+64] + ls[t+128] + ls[t+192];
    float a2 = ls2[t] + ls2[t+64] + ls2[t+128] + ls2[t+192];
    const int cp = (b & 7) * 128;      // XCD-aligned copy
    atomicAdd(&mid1[cp + t], a);
    atomicAdd(&mid1[cp + 64 + t], a2);
  }
}

// ---------------- weight prep ----------------
__global__ __launch_bounds__(256) void wprep_kernel(const float* __restrict__ W3,
    const float* __restrict__ W2, const float* __restrict__ W1c2,
    const float* __restrict__ W2c1,
    unsigned short* __restrict__ W3T, unsigned short* __restrict__ W2T,
    unsigned short* __restrict__ w1T, unsigned short* __restrict__ W2c1T) {
  const int b = blockIdx.x, t = threadIdx.x;
  if (b < 128) {
    for (int n = t; n < 1024; n += 256) W3T[n*128 + b] = f2h(W3[(size_t)b*1024 + n]);
  } else if (b < 132) {
    for (int id = (b-128)*2048 + t; id < (b-127)*2048; id += 256) {
      const int n = id >> 6, k = id & 63;
      W2T[n*64 + k] = f2h(W2[k*128 + n]);
    }
  } else if (b < 136) {
    for (int id = (b-132)*1024 + t; id < (b-131)*1024; id += 256) {
      const int n = id >> 6, k = id & 63;
      w1T[n*64 + k] = f2h(W1c2[k*64 + n]);
    }
  } else {
    for (int id = (b-136)*1024 + t; id < (b-135)*1024; id += 256) {
      const int n = id >> 6, k = id & 63;
      W2c1T[n*64 + k] = f2h(W2c1[k*64 + n]);
    }
  }
}

// ---------------- conv1 layer2 + max: fp16 MFMA; BN finalized from 8-copy mid1 ----------------
__global__ __launch_bounds__(256) void conv1_l2max_mfma(
    const unsigned short* __restrict__ z1h, const float* __restrict__ mid1,
    const float* __restrict__ g1, const float* __restrict__ be1,
    const unsigned short* __restrict__ W2T, const float* __restrict__ b2,
    unsigned short* __restrict__ x1h) {
  __shared__ unsigned short As[128*64];
  __shared__ float scl[64], shl[64];
  const int r0 = blockIdx.x * 128;
  const int t = threadIdx.x;
  const int lane = t & 63, w = t >> 6;
  const int quad = lane >> 4, mcol = lane & 15;
  const float invR = 1.0f / (float)PK;

  if (t < 64) {
    float s = 0.0f, s2 = 0.0f;
    #pragma unroll
    for (int k = 0; k < 8; ++k) { s += mid1[k*128 + t]; s2 += mid1[k*128 + 64 + t]; }
    const float mu  = s * invR;
    const float var = s2 * invR - mu*mu;
    const float sc  = g1[t] * rsqrtf(var + 1e-5f);
    scl[t] = sc; shl[t] = be1[t] - mu*sc;
  }
  __syncthreads();

  {
    const int kb = t & 7, rr = t >> 3;
    float sc[8], sh[8];
    #pragma unroll
    for (int q = 0; q < 8; ++q) { sc[q] = scl[kb*8 + q]; sh[q] = shl[kb*8 + q]; }
    #pragma unroll
    for (int it = 0; it < 4; ++it) {
      const int r = rr + it*32;
      union { uint4 v; unsigned short s[8]; } in;
      in.v = *(const uint4*)(z1h + (size_t)(r0 + r)*64 + kb*8);
      union { unsigned short s[8]; uint4 v; } o;
      #pragma unroll
      for (int q = 0; q < 8; ++q)
        o.s[q] = f2h(fmaxf(h2f(in.s[q])*sc[q] + sh[q], 0.0f));
      *(uint4*)(As + r*64 + ((kb ^ (r & 7)) * 8)) = o.v;
    }
  }
  __syncthreads();

  const int wrow = (w >> 1) * 64;
  const int wncol = (w & 1) * 32;

  f32x4 acc[4][2];
  #pragma unroll
  for (int mi = 0; mi < 4; ++mi)
    #pragma unroll
    for (int ni = 0; ni < 2; ++ni)
      acc[mi][ni] = (f32x4){0.f, 0.f, 0.f, 0.f};

  #pragma unroll
  for (int ks = 0; ks < 2; ++ks) {
    f16x8 af[4], bfr[2];
    #pragma unroll
    for (int mi = 0; mi < 4; ++mi) {
      const int row = wrow + mi*16 + mcol;
      af[mi] = *(const f16x8*)(As + row*64 + (((ks*4 + quad) ^ (row & 7)) * 8));
    }
    #pragma unroll
    for (int ni = 0; ni < 2; ++ni) {
      const int nr = wncol + ni*16 + mcol;
      bfr[ni] = *(const f16x8*)(W2T + nr*64 + ks*32 + quad*8);
    }
    #pragma unroll
    for (int mi = 0; mi < 4; ++mi)
      #pragma unroll
      for (int ni = 0; ni < 2; ++ni)
        acc[mi][ni] = __builtin_amdgcn_mfma_f32_16x16x32_f16(af[mi], bfr[ni], acc[mi][ni], 0, 0, 0);
  }

  float bb[2];
  #pragma unroll
  for (int ni = 0; ni < 2; ++ni) bb[ni] = b2[wncol + ni*16 + mcol];
  #pragma unroll
  for (int mi = 0; mi < 4; ++mi) {
    const int p = blockIdx.x*8 + (w >> 1)*4 + mi;
    #pragma unroll
    for (int ni = 0; ni < 2; ++ni) {
      f32x4 a = acc[mi][ni];
      float m = fmaxf(fmaxf(a[0], a[1]), fmaxf(a[2], a[3]));
      m = fmaxf(m, __shfl_xor(m, 16));
      m = fmaxf(m, __shfl_xor(m, 32));
      if (quad == 0) x1h[(size_t)p*64 + wncol + ni*16 + mcol] = f2h(m + bb[ni]);
    }
  }
}

// ---------------- conv2 layer1: fp16 MFMA (gather + rank-3 rel fixup) + split atomics ----------------
__global__ __launch_bounds__(256) void conv2_l1_mfma(
    const unsigned short* __restrict__ x1h, const int* __restrict__ idx,
    const float* __restrict__ rel, const unsigned short* __restrict__ w1T,
    const float* __restrict__ W1full, const float* __restrict__ b1,
    unsigned short* __restrict__ zah, float* __restrict__ midA) {
  __shared__ unsigned short S[128*64];
  __shared__ int   idxr[128];
  __shared__ float rl[128*3];
  __shared__ float ps[256];
  const int r0 = blockIdx.x * 128;
  const int t = threadIdx.x;
  const int lane = t & 63, w = t >> 6;
  const int quad = lane >> 4, mcol = lane & 15;

  if (t < 128) idxr[t] = idx[r0 + t];
  else if (t < 224) *(float4*)(rl + (t-128)*4) = *(const float4*)(rel + (size_t)r0*3 + (t-128)*4);
  __syncthreads();

  {
    const int kb = t & 7, rr = t >> 3;
    #pragma unroll
    for (int it = 0; it < 4; ++it) {
      const int r = rr + it*32;
      const int gj = idxr[r];
      const uint4 v = *(const uint4*)(x1h + (size_t)gj*64 + kb*8);
      *(uint4*)(S + r*64 + ((kb ^ (r & 7)) * 8)) = v;
    }
  }
  __syncthreads();

  const int wrow = (w >> 1) * 64;
  const int wcol = (w & 1) * 32;

  f16x8 af[2][4], bfr[2][2];
  #pragma unroll
  for (int ks = 0; ks < 2; ++ks)
    #pragma unroll
    for (int mi = 0; mi < 4; ++mi) {
      const int row = wrow + mi*16 + mcol;
      af[ks][mi] = *(const f16x8*)(S + row*64 + (((ks*4 + quad) ^ (row & 7)) * 8));
    }
  #pragma unroll
  for (int ks = 0; ks < 2; ++ks)
    #pragma unroll
    for (int ni = 0; ni < 2; ++ni) {
      const int nr = wcol + ni*16 + mcol;
      bfr[ks][ni] = *(const f16x8*)(w1T + nr*64 + ks*32 + quad*8);
    }

  f32x4 acc[4][2];
  #pragma unroll
  for (int mi = 0; mi < 4; ++mi)
    #pragma unroll
    for (int ni = 0; ni < 2; ++ni)
      acc[mi][ni] = (f32x4){0.f, 0.f, 0.f, 0.f};

  #pragma unroll
  for (int ks = 0; ks < 2; ++ks)
    #pragma unroll
    for (int mi = 0; mi < 4; ++mi)
      #pragma unroll
      for (int ni = 0; ni < 2; ++ni)
        acc[mi][ni] = __builtin_amdgcn_mfma_f32_16x16x32_f16(af[ks][mi], bfr[ks][ni], acc[mi][ni], 0, 0, 0);

  __syncthreads();

  float bb[2], wr0[2], wr1[2], wr2[2];
  #pragma unroll
  for (int ni = 0; ni < 2; ++ni) {
    const int col = wcol + ni*16 + mcol;
    bb[ni]  = b1[col];
    wr0[ni] = W1full[64*64 + col];
    wr1[ni] = W1full[65*64 + col];
    wr2[ni] = W1full[66*64 + col];
  }
  float s[2] = {0,0}, s2[2] = {0,0};
  #pragma unroll
  for (int mi = 0; mi < 4; ++mi) {
    #pragma unroll
    for (int j = 0; j < 4; ++j) {
      const int row = wrow + mi*16 + quad*4 + j;
      const float r0v = rl[row*3], r1v = rl[row*3+1], r2v = rl[row*3+2];
      #pragma unroll
      for (int ni = 0; ni < 2; ++ni) {
        const int col = wcol + ni*16 + mcol;
        const int g = col >> 3, o = col & 7;
        const float v = acc[mi][ni][j] + bb[ni] + r0v*wr0[ni] + r1v*wr1[ni] + r2v*wr2[ni];
        S[row*64 + ((g ^ (row & 7)) << 3) + o] = f2h(v);
        s[ni] += v; s2[ni] += v*v;
      }
    }
  }
  #pragma unroll
  for (int ni = 0; ni < 2; ++ni) {
    s[ni]  += __shfl_xor(s[ni], 16);  s[ni]  += __shfl_xor(s[ni], 32);
    s2[ni] += __shfl_xor(s2[ni], 16); s2[ni] += __shfl_xor(s2[ni], 32);
  }
  if (quad == 0) {
    const int rh = w >> 1;
    #pragma unroll
    for (int ni = 0; ni < 2; ++ni) {
      const int col = wcol + ni*16 + mcol;
      ps[rh*128 + col]      = s[ni];
      ps[rh*128 + 64 + col] = s2[ni];
    }
  }
  __syncthreads();

  #pragma unroll
  for (int i = 0; i < 4; ++i) {
    const int u = i*256 + t;
    const int row = u >> 3, gg = u & 7;
    *(uint4*)(zah + (size_t)(r0 + row)*64 + gg*8) =
        *(const uint4*)(S + row*64 + ((gg ^ (row & 7)) << 3));
  }
  if (t < 128) atomicAdd(&midA[(blockIdx.x & 7)*128 + t], ps[t] + ps[128 + t]);
}

// ---------------- conv2 layer2: fp16 MFMA; BN from 8-copy midA; split atomics to midB ----------------
__global__ __launch_bounds__(256) void conv2_l2_mfma(
    const unsigned short* __restrict__ zah, const float* __restrict__ midA,
    const float* __restrict__ g1, const float* __restrict__ be1,
    const unsigned short* __restrict__ W2T, const float* __restrict__ b2,
    unsigned short* __restrict__ zhb, float* __restrict__ midB) {
  __shared__ unsigned short S[128*128];
  __shared__ float ps[512];
  __shared__ float scl[64], shl[64];
  const int r0 = blockIdx.x * 128;
  const int t = threadIdx.x;
  const int lane = t & 63, w = t >> 6;
  const int quad = lane >> 4, mcol = lane & 15;
  const float invR = 1.0f / (float)PK;

  if (t < 64) {
    float s = 0.0f, s2 = 0.0f;
    #pragma unroll
    for (int k = 0; k < 8; ++k) { s += midA[k*128 + t]; s2 += midA[k*128 + 64 + t]; }
    const float mu  = s * invR;
    const float var = s2 * invR - mu*mu;
    const float sc  = g1[t] * rsqrtf(var + 1e-5f);
    scl[t] = sc; shl[t] = be1[t] - mu*sc;
  }
  __syncthreads();

  {
    const int kb = t & 7, rr = t >> 3;
    float sc[8], sh[8];
    #pragma unroll
    for (int q = 0; q < 8; ++q) { sc[q] = scl[kb*8 + q]; sh[q] = shl[kb*8 + q]; }
    #pragma unroll
    for (int it = 0; it < 4; ++it) {
      const int r = rr + it*32;
      union { uint4 v; unsigned short s[8]; } in;
      in.v = *(const uint4*)(zah + (size_t)(r0 + r)*64 + kb*8);
      union { unsigned short s[8]; uint4 v; } o;
      #pragma unroll
      for (int q = 0; q < 8; ++q)
        o.s[q] = f2h(fmaxf(h2f(in.s[q])*sc[q] + sh[q], 0.0f));
      *(uint4*)(S + r*64 + ((kb ^ (r & 7)) * 8)) = o.v;
    }
  }
  __syncthreads();

  const int wrow = (w >> 1) * 64;
  const int wcol = (w & 1) * 64;

  f16x8 af[2][4], bfr[2][4];
  #pragma unroll
  for (int ks = 0; ks < 2; ++ks)
    #pragma unroll
    for (int mi = 0; mi < 4; ++mi) {
      const int row = wrow + mi*16 + mcol;
      af[ks][mi] = *(const f16x8*)(S + row*64 + (((ks*4 + quad) ^ (row & 7)) * 8));
    }
  #pragma unroll
  for (int ks = 0; ks < 2; ++ks)
    #pragma unroll
    for (int ni = 0; ni < 4; ++ni) {
      const int nr = wcol + ni*16 + mcol;
      bfr[ks][ni] = *(const f16x8*)(W2T + nr*64 + ks*32 + quad*8);
    }

  f32x4 acc[4][4];
  #pragma unroll
  for (int mi = 0; mi < 4; ++mi)
    #pragma unroll
    for (int ni = 0; ni < 4; ++ni)
      acc[mi][ni] = (f32x4){0.f, 0.f, 0.f, 0.f};

  #pragma unroll
  for (int ks = 0; ks < 2; ++ks)
    #pragma unroll
    for (int mi = 0; mi < 4; ++mi)
      #pragma unroll
      for (int ni = 0; ni < 4; ++ni)
        acc[mi][ni] = __builtin_amdgcn_mfma_f32_16x16x32_f16(af[ks][mi], bfr[ks][ni], acc[mi][ni], 0, 0, 0);

  __syncthreads();

  float bb[4];
  #pragma unroll
  for (int ni = 0; ni < 4; ++ni) bb[ni] = b2[wcol + ni*16 + mcol];
  float s[4] = {0,0,0,0}, s2[4] = {0,0,0,0};
  #pragma unroll
  for (int mi = 0; mi < 4; ++mi) {
    #pragma unroll
    for (int ni = 0; ni < 4; ++ni) {
      const int col = wcol + ni*16 + mcol;
      const int g = col >> 3, o = col & 7;
      #pragma unroll
      for (int j = 0; j < 4; ++j) {
        const int row = wrow + mi*16 + quad*4 + j;
        const float v = acc[mi][ni][j] + bb[ni];
        S[row*128 + ((g ^ (row & 15)) << 3) + o] = f2h(v);
        s[ni] += v; s2[ni] += v*v;
      }
    }
  }
  #pragma unroll
  for (int ni = 0; ni < 4; ++ni) {
    s[ni]  += __shfl_xor(s[ni], 16);  s[ni]  += __shfl_xor(s[ni], 32);
    s2[ni] += __shfl_xor(s2[ni], 16); s2[ni] += __shfl_xor(s2[ni], 32);
  }
  if (quad == 0) {
    const int rh = w >> 1;
    #pragma unroll
    for (int ni = 0; ni < 4; ++ni) {
      const int col = wcol + ni*16 + mcol;
      ps[rh*256 + col]       = s[ni];
      ps[rh*256 + 128 + col] = s2[ni];
    }
  }
  __syncthreads();

  #pragma unroll
  for (int i = 0; i < 8; ++i) {
    const int u = i*256 + t;
    const int row = u >> 4, gg = u & 15;
    *(uint4*)(zhb + (size_t)(r0 + row)*128 + gg*8) =
        *(const uint4*)(S + row*128 + ((gg ^ (row & 15)) << 3));
  }
  atomicAdd(&midB[(blockIdx.x & 7)*256 + t], ps[t] + ps[256 + t]);
}

// ---------------- conv2 layer3 + full max fusion: round-13 body; BN from 8-copy midB ----------------
// NOTE (3x confirmed): any added per-iter register state spills — keep acc at 32 AGPR.
__global__ __launch_bounds__(256, 3) void conv2_l3max_mfma(
    const unsigned short* __restrict__ zhb, const float* __restrict__ midB,
    const float* __restrict__ g2, const float* __restrict__ be2,
    const unsigned short* __restrict__ W3T,
    float* __restrict__ pmax2) {
  __shared__ unsigned short As[128*128];
  __shared__ float pm[1024];   // [rowhalf][512]
  __shared__ float scl[128], shl[128];
  const int rb = blockIdx.x & 1023, ch = blockIdx.x >> 10;
  const int r0 = rb * 128;
  const int t = threadIdx.x;
  const int lane = t & 63, w = t >> 6;
  const int quad = lane >> 4, mcol = lane & 15;
  const float invR = 1.0f / (float)PK;

  #pragma unroll
  for (int i = 0; i < 4; ++i) pm[i*256 + t] = -INFINITY;

  if (t < 128) {
    float s = 0.0f, s2 = 0.0f;
    #pragma unroll
    for (int k = 0; k < 8; ++k) { s += midB[k*256 + t]; s2 += midB[k*256 + 128 + t]; }
    const float mu  = s * invR;
    const float var = s2 * invR - mu*mu;
    const float sc  = g2[t] * rsqrtf(var + 1e-5f);
    scl[t] = sc; shl[t] = be2[t] - mu*sc;
  }
  __syncthreads();

  {
    const int kb = t & 15, rr = t >> 4;
    float sc[8], sh[8];
    #pragma unroll
    for (int q = 0; q < 8; ++q) { sc[q] = scl[kb*8 + q]; sh[q] = shl[kb*8 + q]; }
    #pragma unroll
    for (int it = 0; it < 8; ++it) {
      const int r = rr + it*16;
      union { uint4 v; unsigned short s[8]; } in;
      in.v = *(const uint4*)(zhb + (size_t)(r0 + r)*128 + kb*8);
      union { unsigned short s[8]; uint4 v; } o;
      #pragma unroll
      for (int q = 0; q < 8; ++q)
        o.s[q] = f2h(fmaxf(h2f(in.s[q])*sc[q] + sh[q], 0.0f));
      *(uint4*)(As + r*128 + ((kb ^ (r & 7)) * 8)) = o.v;
    }
  }
  __syncthreads();

  const int wrow = (w >> 1) * 64;
  const int wncol = (w & 1) * 32;
  const int rh = w >> 1;

  #pragma unroll 1
  for (int chunk = 0; chunk < 8; ++chunk) {
    const int n0 = ch*512 + chunk*64;

    f32x4 acc[4][2];
    #pragma unroll
    for (int mi = 0; mi < 4; ++mi)
      #pragma unroll
      for (int ni = 0; ni < 2; ++ni)
        acc[mi][ni] = (f32x4){0.f, 0.f, 0.f, 0.f};

    #pragma unroll
    for (int ks = 0; ks < 4; ++ks) {
      f16x8 bfr[2], af[4];
      #pragma unroll
      for (int ni = 0; ni < 2; ++ni) {
        const int nr = n0 + wncol + ni*16 + mcol;
        bfr[ni] = *(const f16x8*)(W3T + (size_t)nr*128 + ks*32 + quad*8);
      }
      #pragma unroll
      for (int mi = 0; mi < 4; ++mi) {
        const int row = wrow + mi*16 + mcol;
        af[mi] = *(const f16x8*)(As + row*128 + (((ks*4 + quad) ^ (row & 7)) * 8));
      }
      #pragma unroll
      for (int mi = 0; mi < 4; ++mi)
        #pragma unroll
        for (int ni = 0; ni < 2; ++ni)
          acc[mi][ni] = __builtin_amdgcn_mfma_f32_16x16x32_f16(af[mi], bfr[ni], acc[mi][ni], 0, 0, 0);
    }

    #pragma unroll
    for (int ni = 0; ni < 2; ++ni) {
      float m4 = -INFINITY;
      #pragma unroll
      for (int mi = 0; mi < 4; ++mi) {
        f32x4 a = acc[mi][ni];
        m4 = fmaxf(m4, fmaxf(fmaxf(a[0], a[1]), fmaxf(a[2], a[3])));
      }
      m4 = fmaxf(m4, __shfl_xor(m4, 16));
      m4 = fmaxf(m4, __shfl_xor(m4, 32));
      if (quad == 0) {
        const int pc = rh*512 + chunk*64 + wncol + ni*16 + mcol;
        pm[pc] = fmaxf(pm[pc], m4);
      }
    }
  }
  __syncthreads();

  pmax2[(size_t)rb*1024 + ch*512 + t]       = fmaxf(pm[t], pm[512 + t]);
  pmax2[(size_t)rb*1024 + ch*512 + 256 + t] = fmaxf(pm[256 + t], pm[768 + t]);
}

// ---------------- final pool: max over 128 row-blocks per graph + b3 ----------------
__global__ __launch_bounds__(256) void pool_final_kernel(const float* __restrict__ pmax2,
    const float* __restrict__ b3, float* __restrict__ g) {
  const int b = blockIdx.x >> 2, q = blockIdx.x & 3;
  const int c = q*256 + threadIdx.x;
  const float* p = pmax2 + (size_t)b*128*1024 + c;
  float m = -INFINITY;
  for (int rb = 0; rb < 128; ++rb) m = fmaxf(m, p[(size_t)rb*1024]);
  g[b*1024 + c] = m + b3[c];
}

// ---------------- final linear (partials over c-quarters) ----------------
__global__ __launch_bounds__(256) void lin_kernel(const float* __restrict__ g,
    const float* __restrict__ W, float* __restrict__ zpart) {
  const int b = blockIdx.x >> 2, q = blockIdx.x & 3;
  const int o = threadIdx.x;
  const float* gb = g + b*1024 + q*256;
  const float* Wq = W + q*256*256;
  float acc = 0.0f;
  for (int c = 0; c < 256; ++c) acc += gb[c] * Wq[c*256 + o];
  zpart[blockIdx.x*256 + o] = acc;
}

// ---------------- final BN(8 rows) + relu ----------------
__global__ __launch_bounds__(256) void final_kernel(const float* __restrict__ zpart,
    const float* __restrict__ lb, const float* __restrict__ lg,
    const float* __restrict__ lbe, float* __restrict__ out) {
  const int o = threadIdx.x;
  float z[NB]; float s = 0.0f, s2 = 0.0f;
  #pragma unroll
  for (int b = 0; b < NB; ++b) {
    float v = lb[o];
    #pragma unroll
    for (int q = 0; q < 4; ++q) v += zpart[(b*4+q)*256 + o];
    z[b] = v; s += v; s2 += v*v;
  }
  const float mu  = s * 0.125f;
  const float var = s2 * 0.125f - mu*mu;
  const float inv = rsqrtf(var + 1e-5f);
  const float sc = lg[o]*inv, sh = lbe[o] - mu*sc;
  #pragma unroll
  for (int b = 0; b < NB; ++b) out[b*256 + o] = fmaxf(z[b]*sc + sh, 0.0f);
}

extern "C" void kernel_launch(void* const* d_in, const int* in_sizes, int n_in,
                              void* d_out, int out_size, void* d_ws, size_t ws_size,
                              hipStream_t stream) {
  const float* pos    = (const float*)d_in[0];
  const float* c1_W1  = (const float*)d_in[2];
  const float* c1_b1  = (const float*)d_in[3];
  const float* c1_g1  = (const float*)d_in[4];
  const float* c1_be1 = (const float*)d_in[5];
  const float* c1_W2  = (const float*)d_in[6];
  const float* c1_b2  = (const float*)d_in[7];
  const float* c2_W1  = (const float*)d_in[8];
  const float* c2_b1  = (const float*)d_in[9];
  const float* c2_g1  = (const float*)d_in[10];
  const float* c2_be1 = (const float*)d_in[11];
  const float* c2_W2  = (const float*)d_in[12];
  const float* c2_b2  = (const float*)d_in[13];
  const float* c2_g2  = (const float*)d_in[14];
  const float* c2_be2 = (const float*)d_in[15];
  const float* c2_W3  = (const float*)d_in[16];
  const float* c2_b3  = (const float*)d_in[17];
  const float* lin_W  = (const float*)d_in[18];
  const float* lin_b  = (const float*)d_in[19];
  const float* lin_g  = (const float*)d_in[20];
  const float* lin_be = (const float*)d_in[21];
  float* out = (float*)d_out;

  char* ws = (char*)d_ws;
  int*   idx     = (int*)  (ws + 0);                 // 512 KB
  float* rel     = (float*)(ws + 524288);            // 1.5 MB
  float* zpart   = (float*)(ws + 2097152 + 2048);    // 8192
  float* gpool   = (float*)(ws + 2097152 + 2048 + 32768);          // 8192
  float* mid1    = (float*)(ws + 2164736);           // 8 x 128 floats (4 KB) } zeroed by
  float* midA    = (float*)(ws + 2164736 + 4096);    // 8 x 128 floats (4 KB) } one
  float* midB    = (float*)(ws + 2164736 + 8192);    // 8 x 256 floats (8 KB) } memset
  unsigned short* W2T   = (unsigned short*)(ws + 2295808);  // 16 KB (conv2 W2)
  unsigned short* w1T   = (unsigned short*)(ws + 2312192);  // 8 KB  (conv2 W1 cols 0..63)
  unsigned short* W2c1T = (unsigned short*)(ws + 2320384);  // 8 KB  (conv1 W2)
  unsigned short* z1h = (unsigned short*)(ws + 2426880);
  unsigned short* zah = (unsigned short*)(ws + 2426880);
  float* pmax2   = (float*)(ws + 2426880);
  unsigned short* x1h = (unsigned short*)(ws + 35981312);  // 1 MB fp16
  unsigned short* zhb = (unsigned short*)(ws + 38078464);  // 33.5 MB fp16 zb
  unsigned short* W3T = (unsigned short*)(ws + 71632896);  // 256 KB

  hipMemsetAsync(ws + 2164736, 0, 16384, stream);   // zero mid1/midA/midB (8 copies each)
  wprep_kernel<<<140, 256, 0, stream>>>(c2_W3, c2_W2, c2_W1, c1_W2, W3T, W2T, w1T, W2c1T);
  knn_conv1_kernel<<<PTS/4, 256, 0, stream>>>(pos, c1_W1, c1_b1, idx, rel, z1h, mid1);
  conv1_l2max_mfma<<<PK/128, 256, 0, stream>>>(z1h, mid1, c1_g1, c1_be1, W2c1T, c1_b2, x1h);
  conv2_l1_mfma<<<PK/128, 256, 0, stream>>>(x1h, idx, rel, w1T, c2_W1, c2_b1, zah, midA);
  conv2_l2_mfma<<<PK/128, 256, 0, stream>>>(zah, midA, c2_g1, c2_be1, W2T, c2_b2, zhb, midB);
  conv2_l3max_mfma<<<PK/64, 256, 0, stream>>>(zhb, midB, c2_g2, c2_be2, W3T, pmax2);
  pool_final_kernel<<<NB*4, 256, 0, stream>>>(pmax2, c2_b3, gpool);
  lin_kernel<<<32, 256, 0, stream>>>(gpool, lin_W, zpart);
  final_kernel<<<1, 256, 0, stream>>>(zpart, lin_b, lin_g, lin_be, out);
}